// Round 2
// baseline (61201.654 us; speedup 1.0000x reference)
//
#include <hip/hip_runtime.h>
#include <hip/hip_bf16.h>

// GraphConvLayer: out = relu(A_norm @ (X@W + b))
// Reassociated: Y = A@X (sparse, ~12.8 nnz/row), out = relu(Y@W + rowsum(A)[n]*b[d])
// x: [1024,543,256] f32; W: [256,256] f32; b: [256]; A: [543,543] f32; out: [1024,543,256] f32

#define NND    543
#define NROWP  640          // padded row count for ws arrays
#define NTILE  128
#define NTILES 5
#define SCROWS 192          // superchunk rows
#define NSC    3
#define SLOTS  16           // fixed CSR slots per (row, superchunk); overflow -> dense fallback
#define BTOT   1024
#define GRID   (BTOT*NTILES)

typedef __attribute__((ext_vector_type(8))) short short8;
typedef __attribute__((ext_vector_type(4))) float f32x4;

// ---- workspace layout (bytes) ----
#define WS_MS   0                                  // u16 [640][3][16]        61440
#define WS_AS   61440                              // f32 [640][3][16]       122880
#define WS_CNT  184320                             // u32 [640][3]             7680
#define WS_RS   192000                             // f32 [640]                2560
#define WS_W    194560                             // bf16[16][8][64][8]     131072
#define WS_NEED 325632

// ---- LDS layout (bytes) ----
#define L_XL    0           // bf16 x_sc [192][256] = 98304 ; Y bf16 [128][256] overlays [0,65536)
#define L_MS    98304       // u16 [128][3][16] = 12288    (bounce overlays after gather)
#define L_AS    110592      // f32 [128][3][16] = 24576
#define L_CNT   135168      // u32 [128][3] = 1536
#define L_RS    136704      // f32 [128] = 512
#define L_TOT   137216
#define BSTRIDE 260         // bounce row stride in floats (pad to break 4-way bank conflict)

__device__ __forceinline__ unsigned short f2bf(float f) {   // RNE f32 -> bf16 bits
  unsigned int u = __builtin_bit_cast(unsigned int, f);
  u += 0x7fffu + ((u >> 16) & 1u);
  return (unsigned short)(u >> 16);
}
__device__ __forceinline__ float bflo(unsigned int u) { return __builtin_bit_cast(float, u << 16); }
__device__ __forceinline__ float bfhi(unsigned int u) { return __builtin_bit_cast(float, u & 0xffff0000u); }

// ---------------- prep: padded SoA CSR + rowsum ----------------
__global__ void prep_csr(const float* __restrict__ A, char* __restrict__ ws) {
  const int n = blockIdx.x * 128 + threadIdx.x;
  if (n >= NROWP) return;
  unsigned short* ms = (unsigned short*)(ws + WS_MS) + n * (NSC * SLOTS);
  float* as = (float*)(ws + WS_AS) + n * (NSC * SLOTS);
  unsigned* cn = (unsigned*)(ws + WS_CNT) + n * NSC;
  float* rs = (float*)(ws + WS_RS);
  if (n >= NND) {
    for (int k = 0; k < NSC * SLOTS; k++) { ms[k] = 0; as[k] = 0.f; }
    cn[0] = cn[1] = cn[2] = 0; rs[n] = 0.f;
    return;
  }
  const float* arow = A + (size_t)n * NND;
  float s = 0.f;
  for (int sc = 0; sc < NSC; sc++) {
    const int mb = sc * SCROWS;
    const int rows = min(SCROWS, NND - mb);
    int cnt = 0;
    for (int m = 0; m < rows; m++) {
      const float a = arow[mb + m];
      s += a;
      if (a != 0.f) {
        if (cnt < SLOTS) { ms[sc * SLOTS + cnt] = (unsigned short)m; as[sc * SLOTS + cnt] = a; }
        cnt++;
      }
    }
    for (int k = min(cnt, SLOTS); k < SLOTS; k++) { ms[sc * SLOTS + k] = 0; as[sc * SLOTS + k] = 0.f; }
    cn[sc] = (cnt <= SLOTS) ? (unsigned)((cnt + 3) & ~3) : 0xFFFFFFFFu;
  }
  rs[n] = s;
}

// ---------------- prep: W -> bf16 in MFMA B-fragment layout ----------------
__global__ void prep_w(const float* __restrict__ W, char* __restrict__ ws) {
  const int t = blockIdx.x * 256 + threadIdx.x;
  if (t >= 16 * 8 * 64) return;
  const int lane = t & 63, ks = (t >> 6) & 7, g = t >> 9;
  const int krow = (lane >> 4) * 8, col = g * 16 + (lane & 15);
  unsigned short* dst = (unsigned short*)(ws + WS_W) + t * 8;
  #pragma unroll
  for (int e = 0; e < 8; e++) dst[e] = f2bf(W[(ks * 32 + krow + e) * 256 + col]);
}

// ---------------- main ----------------
__global__ __launch_bounds__(1024, 4)   // 16 waves, 1 block/CU (LDS 137KB), VGPR<=128
void gcn_main(const float* __restrict__ x, const float* __restrict__ Wm,
              const float* __restrict__ bias, const float* __restrict__ A,
              float* __restrict__ out, const char* __restrict__ ws, int use_ws)
{
  __shared__ __align__(16) char lds[L_TOT];
  unsigned short* xl = (unsigned short*)(lds + L_XL);     // u16 units
  unsigned short* msl = (unsigned short*)(lds + L_MS);
  float* asl = (float*)(lds + L_AS);
  unsigned* cnl = (unsigned*)(lds + L_CNT);
  float* rsl = (float*)(lds + L_RS);
  float* bounce = (float*)(lds + L_MS);                   // overlays ms/as after gather

  const int tid = threadIdx.x;
  const int w = tid >> 6, lane = tid & 63;
  // XCD swizzle: consecutive L (5 tiles of one bt) on same XCD; 32 blocks/XCD = 6.4 bts -> L2-fit
  const int p = blockIdx.x;
  const int L = (p & 7) * (GRID / 8) + (p >> 3);
  const int bt = L / NTILES;
  const int tile = L - bt * NTILES;
  const int n0 = tile * NTILE;

  // ---------- phase 0: lists/rowsum into LDS ----------
  if (use_ws) {
    const unsigned* msrc = (const unsigned*)(ws + WS_MS) + (size_t)n0 * 24;   // 24 u32/row
    unsigned* mdst = (unsigned*)msl;
    for (int t = tid; t < NTILE * 24; t += 1024) mdst[t] = msrc[t];
    const f32x4* asrc = (const f32x4*)(ws + WS_AS + (size_t)n0 * 192);        // 12 f32x4/row
    f32x4* adst = (f32x4*)asl;
    for (int t = tid; t < NTILE * 12; t += 1024) adst[t] = asrc[t];
    const unsigned* csrc = (const unsigned*)(ws + WS_CNT) + (size_t)n0 * 3;
    for (int t = tid; t < NTILE * 3; t += 1024) cnl[t] = csrc[t];
    if (tid < NTILE) rsl[tid] = ((const float*)(ws + WS_RS))[n0 + tid];
  }
  __syncthreads();

  // ---------- gather: Y = A@X over 3 superchunks ----------
  f32x4 y[8];
  #pragma unroll
  for (int i = 0; i < 8; i++) y[i] = (f32x4){0.f, 0.f, 0.f, 0.f};
  float racc[8];
  #pragma unroll
  for (int i = 0; i < 8; i++) racc[i] = 0.f;

  const float* xbt = x + (size_t)bt * (NND * 256);

  for (int sc = 0; sc < NSC; sc++) {
    const int mb = sc * SCROWS;
    const int rows = min(SCROWS, NND - mb);
    // stage x superchunk as bf16 (coalesced float4)
    #pragma unroll
    for (int k = 0; k < 12; k++) {
      const int fl = tid + k * 1024;
      const int row = fl >> 6, f4 = fl & 63;
      if (row < rows) {
        const float4 v = *(const float4*)(xbt + (size_t)(mb + row) * 256 + f4 * 4);
        uint2 u;
        u.x = (unsigned)f2bf(v.x) | ((unsigned)f2bf(v.y) << 16);
        u.y = (unsigned)f2bf(v.z) | ((unsigned)f2bf(v.w) << 16);
        *(uint2*)(xl + row * 256 + f4 * 4) = u;
      }
    }
    __syncthreads();
    #pragma unroll
    for (int i = 0; i < 8; i++) {
      const int r = w * 8 + i;
      const int n = n0 + r;
      if (use_ws) {
        const unsigned cnt = cnl[r * 3 + sc];
        if (cnt <= SLOTS) {
          const int sb = (r * 3 + sc) * SLOTS;
          for (unsigned j = 0; j < cnt; j += 4) {
            const ushort4 m4 = *(const ushort4*)(msl + sb + j);
            const f32x4  a4 = *(const f32x4*)(asl + sb + j);
            const uint2 u0 = *(const uint2*)(xl + (int)m4.x * 256 + lane * 4);
            const uint2 u1 = *(const uint2*)(xl + (int)m4.y * 256 + lane * 4);
            const uint2 u2 = *(const uint2*)(xl + (int)m4.z * 256 + lane * 4);
            const uint2 u3 = *(const uint2*)(xl + (int)m4.w * 256 + lane * 4);
            y[i].x += a4.x * bflo(u0.x); y[i].y += a4.x * bfhi(u0.x);
            y[i].z += a4.x * bflo(u0.y); y[i].w += a4.x * bfhi(u0.y);
            y[i].x += a4.y * bflo(u1.x); y[i].y += a4.y * bfhi(u1.x);
            y[i].z += a4.y * bflo(u1.y); y[i].w += a4.y * bfhi(u1.y);
            y[i].x += a4.z * bflo(u2.x); y[i].y += a4.z * bfhi(u2.x);
            y[i].z += a4.z * bflo(u2.y); y[i].w += a4.z * bfhi(u2.y);
            y[i].x += a4.w * bflo(u3.x); y[i].y += a4.w * bfhi(u3.x);
            y[i].z += a4.w * bflo(u3.y); y[i].w += a4.w * bfhi(u3.y);
          }
        } else if (n < NND) {   // rare overflow: dense scan of A row segment
          const float* arow = A + (size_t)n * NND + mb;
          for (int m = 0; m < rows; m++) {
            const float a = arow[m];
            if (a != 0.f) {
              const uint2 u = *(const uint2*)(xl + m * 256 + lane * 4);
              y[i].x += a * bflo(u.x); y[i].y += a * bfhi(u.x);
              y[i].z += a * bflo(u.y); y[i].w += a * bfhi(u.y);
            }
          }
        }
      } else if (n < NND) {     // no-workspace fallback: dense scan + rowsum
        const float* arow = A + (size_t)n * NND + mb;
        #pragma unroll 4
        for (int m = 0; m < rows; m++) {
          const float a = arow[m];
          racc[i] += a;
          if (a != 0.f) {
            const uint2 u = *(const uint2*)(xl + m * 256 + lane * 4);
            y[i].x += a * bflo(u.x); y[i].y += a * bfhi(u.x);
            y[i].z += a * bflo(u.y); y[i].w += a * bfhi(u.y);
          }
        }
      }
    }
    __syncthreads();
  }

  if (!use_ws && lane == 0) {
    #pragma unroll
    for (int i = 0; i < 8; i++) rsl[w * 8 + i] = racc[i];
  }

  // ---------- Y -> LDS bf16 [128][256], XOR-swizzled ----------
  #pragma unroll
  for (int i = 0; i < 8; i++) {
    const int r = w * 8 + i;
    uint2 u;
    u.x = (unsigned)f2bf(y[i].x) | ((unsigned)f2bf(y[i].y) << 16);
    u.y = (unsigned)f2bf(y[i].z) | ((unsigned)f2bf(y[i].w) << 16);
    const int byte = r * 512 + ((lane * 8) ^ ((r & 7) << 4));
    *(uint2*)(lds + byte) = u;
  }
  __syncthreads();

  // ---------- MFMA: out_tile = Y @ W ----------
  const int cl = lane & 15, krow = (lane >> 4) * 8;
  const int d0 = w * 16 + cl;
  short8 wf[8];
  if (use_ws) {
    #pragma unroll
    for (int ks = 0; ks < 8; ks++)
      wf[ks] = *(const short8*)(ws + WS_W + (((w * 8 + ks) * 64 + lane) << 4));
  } else {
    #pragma unroll
    for (int ks = 0; ks < 8; ks++)
      #pragma unroll
      for (int e = 0; e < 8; e++)
        wf[ks][e] = (short)f2bf(Wm[(ks * 32 + krow + e) * 256 + d0]);
  }
  f32x4 acc[8];
  #pragma unroll
  for (int mt = 0; mt < 8; mt++) acc[mt] = (f32x4){0.f, 0.f, 0.f, 0.f};
  #pragma unroll
  for (int ks = 0; ks < 8; ks++) {
    #pragma unroll
    for (int mt = 0; mt < 8; mt++) {
      const int r = mt * 16 + cl;
      const int kb = (ks * 64 + krow * 2) ^ ((r & 7) << 4);
      const short8 af = *(const short8*)(lds + r * 512 + kb);
      acc[mt] = __builtin_amdgcn_mfma_f32_16x16x32_bf16(af, wf[ks], acc[mt], 0, 0, 0);
    }
  }

  // ---------- epilogue: bias + relu, LDS bounce -> full-line coalesced stores ----------
  const float bv = bias[d0];
  for (int mt = 0; mt < 8; mt++) {
    #pragma unroll
    for (int q = 0; q < 4; q++) {
      const int row16 = (lane >> 4) * 4 + q;
      float v = acc[mt][q] + rsl[mt * 16 + row16] * bv;
      bounce[row16 * BSTRIDE + d0] = fmaxf(v, 0.f);
    }
    __syncthreads();
    {
      const int row16 = tid >> 6;
      const int c = (tid & 63) * 4;
      const int n = n0 + mt * 16 + row16;
      if (n < NND) {
        const f32x4 v = *(const f32x4*)(bounce + row16 * BSTRIDE + c);
        *(f32x4*)(out + ((size_t)bt * NND + n) * 256 + c) = v;
      }
    }
    __syncthreads();
  }
}

extern "C" void kernel_launch(void* const* d_in, const int* in_sizes, int n_in,
                              void* d_out, int out_size, void* d_ws, size_t ws_size,
                              hipStream_t stream) {
  const float* x  = (const float*)d_in[0];
  const float* Wm = (const float*)d_in[1];
  const float* b  = (const float*)d_in[2];
  const float* A  = (const float*)d_in[3];
  float* out = (float*)d_out;
  const int use_ws = (d_ws != nullptr && ws_size >= (size_t)WS_NEED) ? 1 : 0;
  if (use_ws) {
    prep_csr<<<(NROWP + 127) / 128, 128, 0, stream>>>(A, (char*)d_ws);
    prep_w<<<(16 * 8 * 64 + 255) / 256, 256, 0, stream>>>(Wm, (char*)d_ws);
  }
  gcn_main<<<GRID, 1024, 0, stream>>>(x, Wm, b, A, out, (const char*)d_ws, use_ws);
}

// Round 3
// 1918.045 us; speedup vs baseline: 31.9084x; 31.9084x over previous
//
#include <hip/hip_runtime.h>
#include <hip/hip_bf16.h>

// GraphConvLayer: out = relu(A_norm @ (X@W + b))
// Reassociated: Y = A@X (sparse gather, ~12.8 nnz/row), out = relu(Y@W + rowsum(A)[n]*b[d])
// x: [1024,543,256] f32; W: [256,256] f32; b: [256]; A: [543,543] f32; out: [1024,543,256] f32

#define NND    543
#define NROWP  640
#define NTILE  64
#define NTILES 9            // ceil(543/64)
#define CAP    48           // CSR slots/row (mean 12.8; overflow -> dense fallback)
#define BTOT   1024
#define GRID   (BTOT*NTILES)   // 9216, %8==0 -> bijective XCD swizzle

typedef __attribute__((ext_vector_type(8))) short short8;
typedef __attribute__((ext_vector_type(4))) float f32x4;

// ---- workspace layout (bytes) ----
#define WS_ENT  0                         // uint2 [640][48] = 245760  {m, f32bits(a)}
#define WS_RS   245760                    // f32 [640]
#define WS_CNT  248320                    // u32 [640]  (padded-to-4 count, or ~0 = overflow)
#define WS_W    250880                    // bf16 fragments [16][8][64][8] = 131072
#define WS_NEED 381952

__device__ __forceinline__ unsigned short f2bf(float f) {   // RNE f32 -> bf16 bits
  unsigned int u = __builtin_bit_cast(unsigned int, f);
  u += 0x7fffu + ((u >> 16) & 1u);
  return (unsigned short)(u >> 16);
}

// ---------------- prep: CSR via wave ballot (one wave per row) ----------------
__global__ void prep_csr(const float* __restrict__ A, char* __restrict__ ws) {
  const int wid = (blockIdx.x * blockDim.x + threadIdx.x) >> 6;   // row
  const int lane = threadIdx.x & 63;
  if (wid >= NROWP) return;
  uint2* ep = (uint2*)(ws + WS_ENT) + (size_t)wid * CAP;
  float* rs = (float*)(ws + WS_RS);
  unsigned* cw = (unsigned*)(ws + WS_CNT);
  if (wid >= NND) { if (lane == 0) { rs[wid] = 0.f; cw[wid] = 0u; } return; }
  const float* arow = A + (size_t)wid * NND;
  float s = 0.f; int cnt = 0;
  for (int m0 = 0; m0 < NND; m0 += 64) {
    const int m = m0 + lane;
    const float a = (m < NND) ? arow[m] : 0.f;
    s += a;
    const unsigned long long mask = __ballot(a != 0.f);
    if (a != 0.f) {
      const int idx = cnt + __popcll(mask & ((1ull << lane) - 1ull));
      if (idx < CAP) ep[idx] = make_uint2((unsigned)m, __builtin_bit_cast(unsigned, a));
    }
    cnt += (int)__popcll(mask);
  }
  #pragma unroll
  for (int o = 32; o > 0; o >>= 1) s += __shfl_xor(s, o);
  const int cpad = (cnt + 3) & ~3;
  if (cnt <= CAP && lane < cpad - cnt) ep[cnt + lane] = make_uint2(0u, 0u); // zero pad (a=0)
  if (lane == 0) { rs[wid] = s; cw[wid] = (cnt <= CAP) ? (unsigned)cpad : 0xFFFFFFFFu; }
}

// ---------------- prep: W -> bf16 in MFMA B-fragment layout ----------------
__global__ void prep_w(const float* __restrict__ W, char* __restrict__ ws) {
  const int t = blockIdx.x * 256 + threadIdx.x;        // 0..8191
  if (t >= 16 * 8 * 64) return;
  const int lane = t & 63, ks = (t >> 6) & 7, g = t >> 9;
  const int krow = (lane >> 4) * 8, col = g * 16 + (lane & 15);
  unsigned short* dst = (unsigned short*)(ws + WS_W) + (size_t)t * 8;
  #pragma unroll
  for (int e = 0; e < 8; e++) dst[e] = f2bf(W[(ks * 32 + krow + e) * 256 + col]);
}

// ---------------- main: fused gather + GEMM ----------------
__global__ __launch_bounds__(256, 4)   // VGPR cap 128; LDS 33KB -> 4 blocks/CU (16 waves)
void gcn_main(const float* __restrict__ x, const float* __restrict__ Wm,
              const float* __restrict__ bias, const float* __restrict__ A,
              float* __restrict__ out, const char* __restrict__ ws, int use_ws)
{
  __shared__ __align__(16) char lds[NTILE * 512 + 256];   // Y bf16 [64][256] swz + rsl f32[64]
  float* rsl = (float*)(lds + NTILE * 512);

  const int tid = threadIdx.x;
  const int w = tid >> 6, lane = tid & 63;
  const int cl = lane & 15, krow = (lane >> 4) * 8;

  // XCD swizzle: 9 tiles of one bt adjacent in L, dispatched ~simultaneously on one XCD
  const int p = blockIdx.x;
  const int L = (p & 7) * (GRID / 8) + (p >> 3);
  const int bt = L / NTILES;
  const int tile = L - bt * NTILES;
  const int n0 = tile * NTILE;

  const float* xbt = x + (size_t)bt * (NND * 256);

  if (tid < NTILE) rsl[tid] = use_ws ? ((const float*)(ws + WS_RS))[n0 + tid] : 0.f;
  __syncthreads();

  // ---- gather: one row at a time, single named accumulator (no register arrays) ----
  const uint2* ents = (const uint2*)(ws + WS_ENT);
  const unsigned* cnts = (const unsigned*)(ws + WS_CNT);

  for (int rr = 0; rr < 16; ++rr) {
    const int r = w * 16 + rr;
    const int n = n0 + r;
    float4 yv = make_float4(0.f, 0.f, 0.f, 0.f);

    if (use_ws) {
      const unsigned cnt = cnts[n];
      const uint2* ep = ents + (size_t)n * CAP;
      if (cnt <= CAP) {
        for (unsigned j = 0; j < cnt; j += 4) {          // cnt padded to multiple of 4
          const uint2 e0 = ep[j], e1 = ep[j + 1], e2 = ep[j + 2], e3 = ep[j + 3];
          const float4 x0 = *(const float4*)(xbt + (e0.x << 8) + (lane << 2));
          const float4 x1 = *(const float4*)(xbt + (e1.x << 8) + (lane << 2));
          const float4 x2 = *(const float4*)(xbt + (e2.x << 8) + (lane << 2));
          const float4 x3 = *(const float4*)(xbt + (e3.x << 8) + (lane << 2));
          const float a0 = __builtin_bit_cast(float, e0.y);
          const float a1 = __builtin_bit_cast(float, e1.y);
          const float a2 = __builtin_bit_cast(float, e2.y);
          const float a3 = __builtin_bit_cast(float, e3.y);
          yv.x += a0 * x0.x; yv.y += a0 * x0.y; yv.z += a0 * x0.z; yv.w += a0 * x0.w;
          yv.x += a1 * x1.x; yv.y += a1 * x1.y; yv.z += a1 * x1.z; yv.w += a1 * x1.w;
          yv.x += a2 * x2.x; yv.y += a2 * x2.y; yv.z += a2 * x2.z; yv.w += a2 * x2.w;
          yv.x += a3 * x3.x; yv.y += a3 * x3.y; yv.z += a3 * x3.z; yv.w += a3 * x3.w;
        }
      } else if (n < NND) {                               // overflow: dense row scan
        const float* arow = A + (size_t)n * NND;
        for (int m = 0; m < NND; ++m) {
          const float a = arow[m];
          if (a != 0.f) {
            const float4 xv = *(const float4*)(xbt + m * 256 + (lane << 2));
            yv.x += a * xv.x; yv.y += a * xv.y; yv.z += a * xv.z; yv.w += a * xv.w;
          }
        }
      }
    } else if (n < NND) {                                 // no-workspace fallback
      const float* arow = A + (size_t)n * NND;
      float s = 0.f;
      for (int m = 0; m < NND; ++m) {
        const float a = arow[m];
        s += a;
        if (a != 0.f) {
          const float4 xv = *(const float4*)(xbt + m * 256 + (lane << 2));
          yv.x += a * xv.x; yv.y += a * xv.y; yv.z += a * xv.z; yv.w += a * xv.w;
        }
      }
      if (lane == 0) rsl[r] = s;
    }

    // Y row -> LDS bf16, XOR-swizzled (byte(feature f) = (f*2) ^ ((r&7)<<4))
    uint2 u;
    u.x = (unsigned)f2bf(yv.x) | ((unsigned)f2bf(yv.y) << 16);
    u.y = (unsigned)f2bf(yv.z) | ((unsigned)f2bf(yv.w) << 16);
    *(uint2*)(lds + r * 512 + ((lane * 8) ^ ((r & 7) << 4))) = u;
  }
  __syncthreads();

  // ---- MFMA: out_tile[64 x 256] = relu(Y@W + rs*b); wave w owns cols w*16+dt*64 ----
  for (int dt = 0; dt < 4; ++dt) {
    const int d0 = dt * 64 + w * 16 + cl;
    short8 wf[8];
    if (use_ws) {
      const int g = dt * 4 + w;
      #pragma unroll
      for (int ks = 0; ks < 8; ks++)
        wf[ks] = *(const short8*)(ws + WS_W + (size_t)(((g * 8 + ks) * 64 + lane) << 4));
    } else {
      #pragma unroll
      for (int ks = 0; ks < 8; ks++) {
        #pragma unroll
        for (int e = 0; e < 8; e++)
          wf[ks][e] = (short)f2bf(Wm[(ks * 32 + krow + e) * 256 + d0]);
      }
    }
    f32x4 acc[4];
    #pragma unroll
    for (int mt = 0; mt < 4; mt++) acc[mt] = (f32x4){0.f, 0.f, 0.f, 0.f};
    #pragma unroll
    for (int ks = 0; ks < 8; ks++) {
      #pragma unroll
      for (int mt = 0; mt < 4; mt++) {
        const int r = mt * 16 + cl;
        const int kb = (ks * 64 + krow * 2) ^ ((r & 7) << 4);
        const short8 af = *(const short8*)(lds + r * 512 + kb);
        acc[mt] = __builtin_amdgcn_mfma_f32_16x16x32_bf16(af, wf[ks], acc[mt], 0, 0, 0);
      }
    }
    const float bv = bias[d0];
    #pragma unroll
    for (int mt = 0; mt < 4; mt++) {
      #pragma unroll
      for (int q = 0; q < 4; q++) {
        const int row = mt * 16 + (lane >> 4) * 4 + q;   // C/D: col=lane&15, row=(lane>>4)*4+q
        const int n = n0 + row;
        if (n < NND) {
          const float v = acc[mt][q] + rsl[row] * bv;
          out[((size_t)bt * NND + n) * 256 + d0] = fmaxf(v, 0.f);
        }
      }
    }
  }
}

extern "C" void kernel_launch(void* const* d_in, const int* in_sizes, int n_in,
                              void* d_out, int out_size, void* d_ws, size_t ws_size,
                              hipStream_t stream) {
  const float* x  = (const float*)d_in[0];
  const float* Wm = (const float*)d_in[1];
  const float* b  = (const float*)d_in[2];
  const float* A  = (const float*)d_in[3];
  float* out = (float*)d_out;
  const int use_ws = (d_ws != nullptr && ws_size >= (size_t)WS_NEED) ? 1 : 0;
  if (use_ws) {
    prep_csr<<<(NROWP * 64 + 255) / 256, 256, 0, stream>>>(A, (char*)d_ws);
    prep_w<<<(16 * 8 * 64 + 255) / 256, 256, 0, stream>>>(Wm, (char*)d_ws);
  }
  gcn_main<<<GRID, 256, 0, stream>>>(x, Wm, b, A, out, (const char*)d_ws, use_ws);
}